// Round 1
// baseline (1445.385 us; speedup 1.0000x reference)
//
#include <hip/hip_runtime.h>
#include <hip/hip_bf16.h>
#include <math.h>

// Problem dims (fixed)
#define BB 2
#define SS 512
#define DD 256
#define FFD 1024
#define HH 4
#define NN 512
#define PP 32
#define KK 16
#define KPP 4
#define RR 64
#define DHH 64
#define TT (BB*SS)   // 1024 tokens

// ---------------------------------------------------------------------------
// LayerNorm: produces n1 = LN(x,g1,b1), n2 = LN(x,g2,b2). One block per token.
// ---------------------------------------------------------------------------
__global__ __launch_bounds__(256) void ln_kernel(
    const float* __restrict__ x,
    const float* __restrict__ g1, const float* __restrict__ b1,
    const float* __restrict__ g2, const float* __restrict__ b2,
    float* __restrict__ n1, float* __restrict__ n2)
{
    int t = blockIdx.x;
    int d = threadIdx.x;
    __shared__ float red[256];
    float v = x[t*DD + d];
    red[d] = v; __syncthreads();
    for (int s = 128; s > 0; s >>= 1) { if (d < s) red[d] += red[d+s]; __syncthreads(); }
    float mu = red[0] * (1.0f/DD);
    __syncthreads();
    float dv = v - mu;
    red[d] = dv*dv; __syncthreads();
    for (int s = 128; s > 0; s >>= 1) { if (d < s) red[d] += red[d+s]; __syncthreads(); }
    float var = red[0] * (1.0f/DD);
    float r = 1.0f / sqrtf(var + 1e-5f);
    n1[t*DD+d] = dv*r*g1[d] + b1[d];
    n2[t*DD+d] = dv*r*g2[d] + b2[d];
}

// ---------------------------------------------------------------------------
// Generic f32 GEMM: C[M,N] = epilogue( A[M,K] @ B + bias )
//   transB==0: B is [K,N] row-major ; transB==1: B is [N,K] row-major
//   mode 0: none; 1: sigmoid; 2: gelu(0.1*val + 0.9*extra); 3: val + extra
// Tiles: 64x64, BK=16, 256 threads, 4x4 per-thread microtile.
// All M,N multiples of 64 and K multiples of 16 in this problem.
// ---------------------------------------------------------------------------
__global__ __launch_bounds__(256) void gemm_kernel(
    const float* __restrict__ A, const float* __restrict__ Bm,
    const float* __restrict__ bias, const float* __restrict__ extra,
    float* __restrict__ C, int M, int Nn, int Kk, int transB, int mode)
{
    __shared__ float As[16][65];
    __shared__ float Bs[16][65];
    int bm = blockIdx.y * 64;
    int bn = blockIdx.x * 64;
    int tid = threadIdx.x;
    int tx = tid & 15, ty = tid >> 4;
    float acc[4][4] = {};
    for (int k0 = 0; k0 < Kk; k0 += 16) {
        #pragma unroll
        for (int e = 0; e < 4; ++e) {
            int lin = e*256 + tid;
            int c = lin & 15, r = lin >> 4;
            As[c][r] = A[(size_t)(bm + r) * Kk + k0 + c];
        }
        if (transB == 0) {
            #pragma unroll
            for (int e = 0; e < 4; ++e) {
                int lin = e*256 + tid;
                int r = lin & 63, c = lin >> 6;
                Bs[c][r] = Bm[(size_t)(k0 + c) * Nn + bn + r];
            }
        } else {
            #pragma unroll
            for (int e = 0; e < 4; ++e) {
                int lin = e*256 + tid;
                int c = lin & 15, r = lin >> 4;
                Bs[c][r] = Bm[(size_t)(bn + r) * Kk + k0 + c];
            }
        }
        __syncthreads();
        #pragma unroll
        for (int kk = 0; kk < 16; ++kk) {
            float a[4], b[4];
            #pragma unroll
            for (int i = 0; i < 4; ++i) a[i] = As[kk][ty*4+i];
            #pragma unroll
            for (int j = 0; j < 4; ++j) b[j] = Bs[kk][tx*4+j];
            #pragma unroll
            for (int i = 0; i < 4; ++i)
                #pragma unroll
                for (int j = 0; j < 4; ++j)
                    acc[i][j] = fmaf(a[i], b[j], acc[i][j]);
        }
        __syncthreads();
    }
    #pragma unroll
    for (int i = 0; i < 4; ++i) {
        int m = bm + ty*4 + i;
        #pragma unroll
        for (int j = 0; j < 4; ++j) {
            int n = bn + tx*4 + j;
            float val = acc[i][j] + (bias ? bias[n] : 0.0f);
            if (mode == 1) {
                val = 1.0f / (1.0f + expf(-val));
            } else if (mode == 2) {
                float z = 0.1f*val + 0.9f*extra[(size_t)m*Nn+n];
                val = 0.5f*z*(1.0f + erff(z*0.70710678118654752f));
            } else if (mode == 3) {
                val = val + extra[(size_t)m*Nn+n];
            }
            C[(size_t)m*Nn + n] = val;
        }
    }
}

// ---------------------------------------------------------------------------
// First attention: softmax(q k^T / 8) v per (b,h,query). Block per (b,h,q).
// q,k,v layout: [B,S,H*DH] (i.e. [B,S,D] with head h at offset h*64).
// ---------------------------------------------------------------------------
__global__ __launch_bounds__(256) void attn_kernel(
    const float* __restrict__ q, const float* __restrict__ k,
    const float* __restrict__ v, float* __restrict__ ctx)
{
    int bi = blockIdx.x;
    int qi = bi & (SS-1);
    int bh = bi >> 9;
    int h = bh & (HH-1);
    int b = bh >> 2;
    int tid = threadIdx.x;
    __shared__ float qv[DHH];
    __shared__ float p[SS];
    __shared__ float red[256];
    const float* qptr = q + ((size_t)(b*SS + qi)*DD) + h*DHH;
    if (tid < DHH) qv[tid] = qptr[tid];
    __syncthreads();
    float s0, s1;
    {
        const float* kp = k + ((size_t)(b*SS + tid)*DD) + h*DHH;
        float acc = 0.f;
        for (int d = 0; d < DHH; ++d) acc = fmaf(qv[d], kp[d], acc);
        s0 = acc * 0.125f;
        kp = k + ((size_t)(b*SS + tid + 256)*DD) + h*DHH;
        acc = 0.f;
        for (int d = 0; d < DHH; ++d) acc = fmaf(qv[d], kp[d], acc);
        s1 = acc * 0.125f;
    }
    red[tid] = fmaxf(s0, s1); __syncthreads();
    for (int s = 128; s > 0; s >>= 1) { if (tid < s) red[tid] = fmaxf(red[tid], red[tid+s]); __syncthreads(); }
    float m = red[0]; __syncthreads();
    float e0 = expf(s0 - m), e1 = expf(s1 - m);
    red[tid] = e0 + e1; __syncthreads();
    for (int s = 128; s > 0; s >>= 1) { if (tid < s) red[tid] += red[tid+s]; __syncthreads(); }
    float inv = 1.0f / red[0];
    __syncthreads();
    p[tid] = e0 * inv; p[tid+256] = e1 * inv;
    __syncthreads();
    int d = tid & 63, g = tid >> 6;
    float acc = 0.f;
    for (int j = g; j < SS; j += 4)
        acc = fmaf(p[j], v[((size_t)(b*SS + j)*DD) + h*DHH + d], acc);
    red[tid] = acc; __syncthreads();
    if (tid < DHH) {
        float r = red[tid] + red[tid+64] + red[tid+128] + red[tid+192];
        ctx[(size_t)(b*SS+qi)*DD + h*DHH + tid] = r;
    }
}

// ---------------------------------------------------------------------------
// Path softmax + score mix + stable top-16 + softmax weights. Block per token.
// Matches jax.lax.top_k ordering (descending value, ties -> lower index).
// ---------------------------------------------------------------------------
__global__ __launch_bounds__(256) void route_kernel(
    const float* __restrict__ n1, const float* __restrict__ ctx,
    const float* __restrict__ Wpath, const float* __restrict__ bpath,
    const float* __restrict__ ts, const float* __restrict__ cs,
    int* __restrict__ topk_idx, float* __restrict__ topk_w,
    float* __restrict__ out_idx)
{
    int t = blockIdx.x, tid = threadIdx.x;
    __shared__ float red0[256], red1[256];
    float a = n1[t*DD+tid], c = ctx[t*DD+tid];
    red0[tid] = a * Wpath[tid*2+0] + c * Wpath[(DD+tid)*2+0];
    red1[tid] = a * Wpath[tid*2+1] + c * Wpath[(DD+tid)*2+1];
    __syncthreads();
    for (int s = 128; s > 0; s >>= 1) {
        if (tid < s) { red0[tid] += red0[tid+s]; red1[tid] += red1[tid+s]; }
        __syncthreads();
    }
    __shared__ float w0s, w1s;
    if (tid == 0) {
        float l0 = red0[0] + bpath[0], l1 = red1[0] + bpath[1];
        float mm = fmaxf(l0, l1);
        float e0 = expf(l0-mm), e1 = expf(l1-mm);
        float is = 1.0f/(e0+e1);
        w0s = e0*is; w1s = e1*is;
    }
    __syncthreads();
    float w0 = w0s, w1 = w1s;
    __shared__ float sc[NN];
    sc[tid]     = w0*ts[t*NN+tid]     + w1*cs[t*NN+tid];
    sc[tid+256] = w0*ts[t*NN+tid+256] + w1*cs[t*NN+tid+256];
    __syncthreads();
    __shared__ float bv_[256]; __shared__ int bi_[256];
    __shared__ float selv[KK]; __shared__ int seli[KK];
    for (int it = 0; it < KK; ++it) {
        float v0 = sc[tid], v1 = sc[tid+256];
        float bv; int bi;
        if (v0 >= v1) { bv = v0; bi = tid; } else { bv = v1; bi = tid+256; }
        bv_[tid] = bv; bi_[tid] = bi;
        __syncthreads();
        for (int s = 128; s > 0; s >>= 1) {
            if (tid < s) {
                float ov = bv_[tid+s]; int oi = bi_[tid+s];
                if (ov > bv_[tid] || (ov == bv_[tid] && oi < bi_[tid])) { bv_[tid] = ov; bi_[tid] = oi; }
            }
            __syncthreads();
        }
        if (tid == 0) { selv[it] = bv_[0]; seli[it] = bi_[0]; sc[bi_[0]] = -3.4e38f; }
        __syncthreads();
    }
    if (tid == 0) {
        float mx = selv[0];
        float e[KK]; float sum = 0.f;
        for (int i = 0; i < KK; ++i) { e[i] = expf(selv[i]-mx); sum += e[i]; }
        float is = 1.0f/sum;
        for (int i = 0; i < KK; ++i) {
            topk_idx[t*KK+i] = seli[i];
            topk_w[t*KK+i]   = e[i]*is;
            out_idx[t*KK+i]  = (float)seli[i];
        }
    }
}

// ---------------------------------------------------------------------------
// InteractionFFN: block per token. Gathers precomputed nq/nk/nv rows for the
// 16 selected neurons, does the K x K per-head attention, gates, aggregates.
// ---------------------------------------------------------------------------
__global__ __launch_bounds__(256) void interact_kernel(
    const float* __restrict__ neurons,
    const float* __restrict__ nqa, const float* __restrict__ nka,
    const float* __restrict__ nva,
    const int* __restrict__ topk_idx, const float* __restrict__ topk_w,
    float* __restrict__ agg)
{
    int t = blockIdx.x, tid = threadIdx.x;
    __shared__ float nq[KK][DD];
    __shared__ float nk[KK][DD];
    __shared__ float nv[KK][DD];
    __shared__ float ps[HH][KK][KK];
    __shared__ float tw[KK];
    __shared__ int sidx[KK];
    if (tid < KK) { tw[tid] = topk_w[t*KK+tid]; sidx[tid] = topk_idx[t*KK+tid]; }
    __syncthreads();
    for (int i = 0; i < KK; ++i) {
        int idx = sidx[i];
        nq[i][tid] = nqa[idx*DD+tid];
        nk[i][tid] = nka[idx*DD+tid];
        nv[i][tid] = nva[idx*DD+tid];
    }
    __syncthreads();
    #pragma unroll
    for (int r = 0; r < 4; ++r) {
        int lin = r*256 + tid;         // (h,i,j)
        int j = lin & 15, i = (lin >> 4) & 15, h = lin >> 8;
        const float* qp = &nq[i][h*DHH];
        const float* kp = &nk[j][h*DHH];
        float acc = 0.f;
        for (int d = 0; d < DHH; ++d) acc = fmaf(qp[d], kp[d], acc);
        ps[h][i][j] = acc * 0.125f;
    }
    __syncthreads();
    if (tid < 64) {                     // softmax over j for each (h,i)
        int h = tid >> 4, i = tid & 15;
        float mx = -3.4e38f;
        for (int j = 0; j < KK; ++j) mx = fmaxf(mx, ps[h][i][j]);
        float sum = 0.f;
        for (int j = 0; j < KK; ++j) { float e = expf(ps[h][i][j]-mx); ps[h][i][j] = e; sum += e; }
        float is = 1.0f/sum;
        for (int j = 0; j < KK; ++j) ps[h][i][j] *= is;
    }
    __syncthreads();
    int d = tid, h = d >> 6;
    float acc = 0.f;
    for (int i = 0; i < KK; ++i) {
        float g = 0.f;
        for (int j = 0; j < KK; ++j) g = fmaf(ps[h][i][j], nv[j][d], g);
        acc += tw[i] * neurons[sidx[i]*DD + d] * g;
    }
    agg[t*DD+d] = acc;
}

// ---------------------------------------------------------------------------
// Pattern stage: block per token. pattern scores, stable top-4, combined,
// LoRA h_mid/h_pat, weighted h_pattern.
// ---------------------------------------------------------------------------
__global__ __launch_bounds__(256) void pattern_kernel(
    const float* __restrict__ aggp, const float* __restrict__ ctxp,
    const float* __restrict__ n2p, const float* __restrict__ PQ,
    const float* __restrict__ Aup, const float* __restrict__ Bup,
    float* __restrict__ combined, float* __restrict__ hpat)
{
    int t = blockIdx.x, tid = threadIdx.x;
    __shared__ float mix[DD], comb[DD];
    __shared__ float ps[PP];
    __shared__ float hmid[KPP][RR];
    __shared__ int tpi[KPP];
    __shared__ float tpw[KPP];
    float a = aggp[t*DD+tid];
    float cx = ctxp[t*DD+tid];
    mix[tid] = 0.03125f * a + 0.5f * cx;   // 0.5/sqrt(256) = 0.03125
    float cb = n2p[t*DD+tid] + a;
    comb[tid] = cb;
    combined[t*DD+tid] = cb;
    __syncthreads();
    if (tid < PP) {
        const float* pq = PQ + tid*DD;
        float acc = 0.f;
        for (int d = 0; d < DD; ++d) acc = fmaf(mix[d], pq[d], acc);
        ps[tid] = acc;
    }
    __syncthreads();
    if (tid == 0) {
        float tmp[PP];
        for (int p = 0; p < PP; ++p) tmp[p] = ps[p];
        float vals[KPP]; int idxs[KPP];
        for (int it = 0; it < KPP; ++it) {
            float bv = -3.4e38f; int bi = 0;
            for (int p = 0; p < PP; ++p) if (tmp[p] > bv) { bv = tmp[p]; bi = p; }
            vals[it] = bv; idxs[it] = bi; tmp[bi] = -3.4e38f;
        }
        float mx = vals[0]; float sum = 0.f; float e[KPP];
        for (int i = 0; i < KPP; ++i) { e[i] = expf(vals[i]-mx); sum += e[i]; }
        float is = 1.0f/sum;
        for (int i = 0; i < KPP; ++i) { tpi[i] = idxs[i]; tpw[i] = e[i]*is; }
    }
    __syncthreads();
    {
        int kp = tid >> 6, r = tid & 63;
        const float* Ap = Aup + (size_t)tpi[kp]*(DD*RR) + r;
        float acc = 0.f;
        for (int d = 0; d < DD; ++d) acc = fmaf(comb[d], Ap[d*RR], acc);
        hmid[kp][r] = acc;
    }
    __syncthreads();
    #pragma unroll
    for (int e = 0; e < 4; ++e) {
        int f = e*256 + tid;
        float acc = 0.f;
        #pragma unroll
        for (int kp = 0; kp < KPP; ++kp) {
            const float* Bp = Bup + (size_t)tpi[kp]*(RR*FFD) + f;
            float part = 0.f;
            for (int r = 0; r < RR; ++r) part = fmaf(hmid[kp][r], Bp[r*FFD], part);
            acc = fmaf(tpw[kp], part, acc);
        }
        hpat[(size_t)t*FFD+f] = acc;
    }
}

// ---------------------------------------------------------------------------
extern "C" void kernel_launch(void* const* d_in, const int* in_sizes, int n_in,
                              void* d_out, int out_size, void* d_ws, size_t ws_size,
                              hipStream_t stream)
{
    const float* x        = (const float*)d_in[0];
    const float* g1       = (const float*)d_in[1];
    const float* b1       = (const float*)d_in[2];
    const float* g2       = (const float*)d_in[3];
    const float* b2       = (const float*)d_in[4];
    const float* Wq       = (const float*)d_in[5];
    const float* bq       = (const float*)d_in[6];
    const float* Wk       = (const float*)d_in[7];
    const float* bk       = (const float*)d_in[8];
    const float* Wv       = (const float*)d_in[9];
    const float* bv       = (const float*)d_in[10];
    const float* Wpath    = (const float*)d_in[11];
    const float* bpath    = (const float*)d_in[12];
    const float* neurons  = (const float*)d_in[13];
    const float* Wnq      = (const float*)d_in[14];
    const float* bnq      = (const float*)d_in[15];
    const float* Wnk      = (const float*)d_in[16];
    const float* bnk      = (const float*)d_in[17];
    const float* Wnv      = (const float*)d_in[18];
    const float* bnv      = (const float*)d_in[19];
    const float* PQ       = (const float*)d_in[20];
    const float* Aup      = (const float*)d_in[21];
    const float* Bup      = (const float*)d_in[22];
    const float* Wub      = (const float*)d_in[23];
    const float* bub      = (const float*)d_in[24];
    const float* Wd       = (const float*)d_in[25];
    const float* bd       = (const float*)d_in[26];

    float* out0    = (float*)d_out;              // [B,S,D] residual output
    float* out_idx = out0 + (size_t)TT*DD;       // [B,S,K] indices (as float)

    // workspace carve-up (floats)
    float* ws = (float*)d_ws;
    float* n1   = ws; ws += TT*DD;
    float* n2   = ws; ws += TT*DD;
    float* qb   = ws; ws += TT*DD;
    float* kb   = ws; ws += TT*DD;
    float* vb   = ws; ws += TT*DD;
    float* ctx  = ws; ws += TT*DD;
    float* ts   = ws; ws += TT*NN;
    float* cs   = ws; ws += TT*NN;
    float* nqa  = ws; ws += NN*DD;
    float* nka  = ws; ws += NN*DD;
    float* nva  = ws; ws += NN*DD;
    float* agg  = ws; ws += TT*DD;
    float* comb = ws; ws += TT*DD;
    float* hpat = ws; ws += TT*FFD;
    float* hb   = ws; ws += TT*FFD;
    float* tkw  = ws; ws += TT*KK;
    int*   tki  = (int*)ws; ws += TT*KK;

    dim3 blk(256);

    // 1. LayerNorms
    ln_kernel<<<TT, blk, 0, stream>>>(x, g1, b1, g2, b2, n1, n2);

    // 2. QKV projections  (M=1024,N=256,K=256)
    gemm_kernel<<<dim3(DD/64, TT/64), blk, 0, stream>>>(n1, Wq, bq, nullptr, qb, TT, DD, DD, 0, 0);
    gemm_kernel<<<dim3(DD/64, TT/64), blk, 0, stream>>>(n1, Wk, bk, nullptr, kb, TT, DD, DD, 0, 0);
    gemm_kernel<<<dim3(DD/64, TT/64), blk, 0, stream>>>(n1, Wv, bv, nullptr, vb, TT, DD, DD, 0, 0);

    // 3. Neuron projections (precompute, M=512,N=256,K=256); nv gets sigmoid
    gemm_kernel<<<dim3(DD/64, NN/64), blk, 0, stream>>>(neurons, Wnq, bnq, nullptr, nqa, NN, DD, DD, 0, 0);
    gemm_kernel<<<dim3(DD/64, NN/64), blk, 0, stream>>>(neurons, Wnk, bnk, nullptr, nka, NN, DD, DD, 0, 0);
    gemm_kernel<<<dim3(DD/64, NN/64), blk, 0, stream>>>(neurons, Wnv, bnv, nullptr, nva, NN, DD, DD, 0, 1);

    // 4. Attention -> context
    attn_kernel<<<BB*HH*SS, blk, 0, stream>>>(qb, kb, vb, ctx);

    // 5. token/context scores vs neurons^T (M=1024,N=512,K=256, transB)
    gemm_kernel<<<dim3(NN/64, TT/64), blk, 0, stream>>>(n1,  neurons, nullptr, nullptr, ts, TT, NN, DD, 1, 0);
    gemm_kernel<<<dim3(NN/64, TT/64), blk, 0, stream>>>(ctx, neurons, nullptr, nullptr, cs, TT, NN, DD, 1, 0);

    // 6. path weights + mix + top-16
    route_kernel<<<TT, blk, 0, stream>>>(n1, ctx, Wpath, bpath, ts, cs, tki, tkw, out_idx);

    // 7. interaction FFN -> aggregated
    interact_kernel<<<TT, blk, 0, stream>>>(neurons, nqa, nka, nva, tki, tkw, agg);

    // 8. pattern LoRA -> combined, h_pattern
    pattern_kernel<<<TT, blk, 0, stream>>>(agg, ctx, n2, PQ, Aup, Bup, comb, hpat);

    // 9. h = gelu(0.1*(combined@Wub+bub) + 0.9*h_pattern)   (M=1024,N=1024,K=256)
    gemm_kernel<<<dim3(FFD/64, TT/64), blk, 0, stream>>>(comb, Wub, bub, hpat, hb, TT, FFD, DD, 0, 2);

    // 10. out = x + h@Wd + bd   (M=1024,N=256,K=1024) -> d_out
    gemm_kernel<<<dim3(DD/64, TT/64), blk, 0, stream>>>(hb, Wd, bd, x, out0, TT, DD, FFD, 0, 3);
}

// Round 2
// 670.090 us; speedup vs baseline: 2.1570x; 2.1570x over previous
//
#include <hip/hip_runtime.h>
#include <hip/hip_bf16.h>
#include <math.h>

// Problem dims (fixed)
#define BB 2
#define SS 512
#define DD 256
#define FFD 1024
#define HH 4
#define NN 512
#define PP 32
#define KK 16
#define KPP 4
#define RR 64
#define DHH 64
#define TT (BB*SS)   // 1024 tokens

// ---------------------------------------------------------------------------
// LayerNorm: produces n1 = LN(x,g1,b1), n2 = LN(x,g2,b2). One block per token.
// ---------------------------------------------------------------------------
__global__ __launch_bounds__(256) void ln_kernel(
    const float* __restrict__ x,
    const float* __restrict__ g1, const float* __restrict__ b1,
    const float* __restrict__ g2, const float* __restrict__ b2,
    float* __restrict__ n1, float* __restrict__ n2)
{
    int t = blockIdx.x;
    int d = threadIdx.x;
    __shared__ float red[256];
    float v = x[t*DD + d];
    red[d] = v; __syncthreads();
    for (int s = 128; s > 0; s >>= 1) { if (d < s) red[d] += red[d+s]; __syncthreads(); }
    float mu = red[0] * (1.0f/DD);
    __syncthreads();
    float dv = v - mu;
    red[d] = dv*dv; __syncthreads();
    for (int s = 128; s > 0; s >>= 1) { if (d < s) red[d] += red[d+s]; __syncthreads(); }
    float var = red[0] * (1.0f/DD);
    float r = 1.0f / sqrtf(var + 1e-5f);
    n1[t*DD+d] = dv*r*g1[d] + b1[d];
    n2[t*DD+d] = dv*r*g2[d] + b2[d];
}

// ---------------------------------------------------------------------------
// Shared GEMM body: C[M,N] = epilogue( A[M,K] @ B + bias )
//   transB==0: B is [K,N] row-major ; transB==1: B is [N,K] row-major
//   mode 0: none; 1: sigmoid; 2: gelu(0.1*val + 0.9*extra); 3: val + extra
// Tiles: 64x64, BK=16, 256 threads, 4x4 per-thread microtile.
// ---------------------------------------------------------------------------
__device__ __forceinline__ void gemm_body(
    const float* __restrict__ A, const float* __restrict__ Bm,
    const float* __restrict__ bias, const float* __restrict__ extra,
    float* __restrict__ C, int M, int Nn, int Kk, int transB, int mode)
{
    __shared__ float As[16][65];
    __shared__ float Bs[16][65];
    int bm = blockIdx.y * 64;
    int bn = blockIdx.x * 64;
    int tid = threadIdx.x;
    int tx = tid & 15, ty = tid >> 4;
    float acc[4][4] = {};
    for (int k0 = 0; k0 < Kk; k0 += 16) {
        #pragma unroll
        for (int e = 0; e < 4; ++e) {
            int lin = e*256 + tid;
            int c = lin & 15, r = lin >> 4;
            As[c][r] = A[(size_t)(bm + r) * Kk + k0 + c];
        }
        if (transB == 0) {
            #pragma unroll
            for (int e = 0; e < 4; ++e) {
                int lin = e*256 + tid;
                int r = lin & 63, c = lin >> 6;
                Bs[c][r] = Bm[(size_t)(k0 + c) * Nn + bn + r];
            }
        } else {
            #pragma unroll
            for (int e = 0; e < 4; ++e) {
                int lin = e*256 + tid;
                int c = lin & 15, r = lin >> 4;
                Bs[c][r] = Bm[(size_t)(bn + r) * Kk + k0 + c];
            }
        }
        __syncthreads();
        #pragma unroll
        for (int kk = 0; kk < 16; ++kk) {
            float a[4], b[4];
            #pragma unroll
            for (int i = 0; i < 4; ++i) a[i] = As[kk][ty*4+i];
            #pragma unroll
            for (int j = 0; j < 4; ++j) b[j] = Bs[kk][tx*4+j];
            #pragma unroll
            for (int i = 0; i < 4; ++i)
                #pragma unroll
                for (int j = 0; j < 4; ++j)
                    acc[i][j] = fmaf(a[i], b[j], acc[i][j]);
        }
        __syncthreads();
    }
    #pragma unroll
    for (int i = 0; i < 4; ++i) {
        int m = bm + ty*4 + i;
        #pragma unroll
        for (int j = 0; j < 4; ++j) {
            int n = bn + tx*4 + j;
            float val = acc[i][j] + (bias ? bias[n] : 0.0f);
            if (mode == 1) {
                val = 1.0f / (1.0f + expf(-val));
            } else if (mode == 2) {
                float z = 0.1f*val + 0.9f*extra[(size_t)m*Nn+n];
                val = 0.5f*z*(1.0f + erff(z*0.70710678118654752f));
            } else if (mode == 3) {
                val = val + extra[(size_t)m*Nn+n];
            }
            C[(size_t)m*Nn + n] = val;
        }
    }
}

__global__ __launch_bounds__(256) void gemm_kernel(
    const float* __restrict__ A, const float* __restrict__ Bm,
    const float* __restrict__ bias, const float* __restrict__ extra,
    float* __restrict__ C, int M, int Nn, int Kk, int transB, int mode)
{
    gemm_body(A, Bm, bias, extra, C, M, Nn, Kk, transB, mode);
}

// Batched-by-z variant: up to 3 independent (A,B,bias,C,mode) sets, same shape.
struct GemmSet { const float* A; const float* B; const float* bias; float* C; int mode; };

__global__ __launch_bounds__(256) void gemm3_kernel(
    GemmSet s0, GemmSet s1, GemmSet s2, int M, int Nn, int Kk, int transB)
{
    GemmSet s = (blockIdx.z == 0) ? s0 : ((blockIdx.z == 1) ? s1 : s2);
    gemm_body(s.A, s.B, s.bias, nullptr, s.C, M, Nn, Kk, transB, s.mode);
}

// ---------------------------------------------------------------------------
// First attention: softmax(q k^T / 8) v per (b,h,query). Block per (b,h,q).
// ---------------------------------------------------------------------------
__global__ __launch_bounds__(256) void attn_kernel(
    const float* __restrict__ q, const float* __restrict__ k,
    const float* __restrict__ v, float* __restrict__ ctx)
{
    int bi = blockIdx.x;
    int qi = bi & (SS-1);
    int bh = bi >> 9;
    int h = bh & (HH-1);
    int b = bh >> 2;
    int tid = threadIdx.x;
    __shared__ float qv[DHH];
    __shared__ float p[SS];
    __shared__ float red[256];
    const float* qptr = q + ((size_t)(b*SS + qi)*DD) + h*DHH;
    if (tid < DHH) qv[tid] = qptr[tid];
    __syncthreads();
    float s0, s1;
    {
        const float* kp = k + ((size_t)(b*SS + tid)*DD) + h*DHH;
        float acc = 0.f;
        for (int d = 0; d < DHH; ++d) acc = fmaf(qv[d], kp[d], acc);
        s0 = acc * 0.125f;
        kp = k + ((size_t)(b*SS + tid + 256)*DD) + h*DHH;
        acc = 0.f;
        for (int d = 0; d < DHH; ++d) acc = fmaf(qv[d], kp[d], acc);
        s1 = acc * 0.125f;
    }
    red[tid] = fmaxf(s0, s1); __syncthreads();
    for (int s = 128; s > 0; s >>= 1) { if (tid < s) red[tid] = fmaxf(red[tid], red[tid+s]); __syncthreads(); }
    float m = red[0]; __syncthreads();
    float e0 = expf(s0 - m), e1 = expf(s1 - m);
    red[tid] = e0 + e1; __syncthreads();
    for (int s = 128; s > 0; s >>= 1) { if (tid < s) red[tid] += red[tid+s]; __syncthreads(); }
    float inv = 1.0f / red[0];
    __syncthreads();
    p[tid] = e0 * inv; p[tid+256] = e1 * inv;
    __syncthreads();
    int d = tid & 63, g = tid >> 6;
    float acc = 0.f;
    for (int j = g; j < SS; j += 4)
        acc = fmaf(p[j], v[((size_t)(b*SS + j)*DD) + h*DHH + d], acc);
    red[tid] = acc; __syncthreads();
    if (tid < DHH) {
        float r = red[tid] + red[tid+64] + red[tid+128] + red[tid+192];
        ctx[(size_t)(b*SS+qi)*DD + h*DHH + tid] = r;
    }
}

// ---------------------------------------------------------------------------
// Path softmax + score mix + stable top-16 + softmax weights. Block per token.
// ---------------------------------------------------------------------------
__global__ __launch_bounds__(256) void route_kernel(
    const float* __restrict__ n1, const float* __restrict__ ctx,
    const float* __restrict__ Wpath, const float* __restrict__ bpath,
    const float* __restrict__ ts, const float* __restrict__ cs,
    int* __restrict__ topk_idx, float* __restrict__ topk_w,
    float* __restrict__ out_idx)
{
    int t = blockIdx.x, tid = threadIdx.x;
    __shared__ float red0[256], red1[256];
    float a = n1[t*DD+tid], c = ctx[t*DD+tid];
    red0[tid] = a * Wpath[tid*2+0] + c * Wpath[(DD+tid)*2+0];
    red1[tid] = a * Wpath[tid*2+1] + c * Wpath[(DD+tid)*2+1];
    __syncthreads();
    for (int s = 128; s > 0; s >>= 1) {
        if (tid < s) { red0[tid] += red0[tid+s]; red1[tid] += red1[tid+s]; }
        __syncthreads();
    }
    __shared__ float w0s, w1s;
    if (tid == 0) {
        float l0 = red0[0] + bpath[0], l1 = red1[0] + bpath[1];
        float mm = fmaxf(l0, l1);
        float e0 = expf(l0-mm), e1 = expf(l1-mm);
        float is = 1.0f/(e0+e1);
        w0s = e0*is; w1s = e1*is;
    }
    __syncthreads();
    float w0 = w0s, w1 = w1s;
    __shared__ float sc[NN];
    sc[tid]     = w0*ts[t*NN+tid]     + w1*cs[t*NN+tid];
    sc[tid+256] = w0*ts[t*NN+tid+256] + w1*cs[t*NN+tid+256];
    __syncthreads();
    __shared__ float bv_[256]; __shared__ int bi_[256];
    __shared__ float selv[KK]; __shared__ int seli[KK];
    for (int it = 0; it < KK; ++it) {
        float v0 = sc[tid], v1 = sc[tid+256];
        float bv; int bi;
        if (v0 >= v1) { bv = v0; bi = tid; } else { bv = v1; bi = tid+256; }
        bv_[tid] = bv; bi_[tid] = bi;
        __syncthreads();
        for (int s = 128; s > 0; s >>= 1) {
            if (tid < s) {
                float ov = bv_[tid+s]; int oi = bi_[tid+s];
                if (ov > bv_[tid] || (ov == bv_[tid] && oi < bi_[tid])) { bv_[tid] = ov; bi_[tid] = oi; }
            }
            __syncthreads();
        }
        if (tid == 0) { selv[it] = bv_[0]; seli[it] = bi_[0]; sc[bi_[0]] = -3.4e38f; }
        __syncthreads();
    }
    if (tid == 0) {
        float mx = selv[0];
        float e[KK]; float sum = 0.f;
        for (int i = 0; i < KK; ++i) { e[i] = expf(selv[i]-mx); sum += e[i]; }
        float is = 1.0f/sum;
        for (int i = 0; i < KK; ++i) {
            topk_idx[t*KK+i] = seli[i];
            topk_w[t*KK+i]   = e[i]*is;
            out_idx[t*KK+i]  = (float)seli[i];
        }
    }
}

// ---------------------------------------------------------------------------
// InteractionFFN: block per token.
// ---------------------------------------------------------------------------
__global__ __launch_bounds__(256) void interact_kernel(
    const float* __restrict__ neurons,
    const float* __restrict__ nqa, const float* __restrict__ nka,
    const float* __restrict__ nva,
    const int* __restrict__ topk_idx, const float* __restrict__ topk_w,
    float* __restrict__ agg)
{
    int t = blockIdx.x, tid = threadIdx.x;
    __shared__ float nq[KK][DD];
    __shared__ float nk[KK][DD];
    __shared__ float nv[KK][DD];
    __shared__ float ps[HH][KK][KK];
    __shared__ float tw[KK];
    __shared__ int sidx[KK];
    if (tid < KK) { tw[tid] = topk_w[t*KK+tid]; sidx[tid] = topk_idx[t*KK+tid]; }
    __syncthreads();
    for (int i = 0; i < KK; ++i) {
        int idx = sidx[i];
        nq[i][tid] = nqa[idx*DD+tid];
        nk[i][tid] = nka[idx*DD+tid];
        nv[i][tid] = nva[idx*DD+tid];
    }
    __syncthreads();
    #pragma unroll
    for (int r = 0; r < 4; ++r) {
        int lin = r*256 + tid;         // (h,i,j)
        int j = lin & 15, i = (lin >> 4) & 15, h = lin >> 8;
        const float* qp = &nq[i][h*DHH];
        const float* kp = &nk[j][h*DHH];
        float acc = 0.f;
        #pragma unroll 8
        for (int d = 0; d < DHH; ++d) acc = fmaf(qp[d], kp[d], acc);
        ps[h][i][j] = acc * 0.125f;
    }
    __syncthreads();
    if (tid < 64) {                     // softmax over j for each (h,i)
        int h = tid >> 4, i = tid & 15;
        float mx = -3.4e38f;
        for (int j = 0; j < KK; ++j) mx = fmaxf(mx, ps[h][i][j]);
        float sum = 0.f;
        for (int j = 0; j < KK; ++j) { float e = expf(ps[h][i][j]-mx); ps[h][i][j] = e; sum += e; }
        float is = 1.0f/sum;
        for (int j = 0; j < KK; ++j) ps[h][i][j] *= is;
    }
    __syncthreads();
    int d = tid, h = d >> 6;
    float acc = 0.f;
    for (int i = 0; i < KK; ++i) {
        float g = 0.f;
        #pragma unroll
        for (int j = 0; j < KK; ++j) g = fmaf(ps[h][i][j], nv[j][d], g);
        acc += tw[i] * neurons[sidx[i]*DD + d] * g;
    }
    agg[t*DD+d] = acc;
}

// ---------------------------------------------------------------------------
// Pattern stage (REWRITTEN): block per token.
//  - parallel score phase (8 groups x 32 patterns)
//  - top-4 selection in LDS (no private arrays -> no spills)
//  - tpw folded into hmid
//  - h_pat phase: float4 B loads, unroll 8, 4 f per thread
// ---------------------------------------------------------------------------
__global__ __launch_bounds__(256) void pattern_kernel(
    const float* __restrict__ aggp, const float* __restrict__ ctxp,
    const float* __restrict__ n2p, const float* __restrict__ PQ,
    const float* __restrict__ Aup, const float* __restrict__ Bup,
    float* __restrict__ combined, float* __restrict__ hpat)
{
    int t = blockIdx.x, tid = threadIdx.x;
    __shared__ float mix[DD], comb[DD];
    __shared__ float ps[PP];
    __shared__ float psp[8][33];
    __shared__ float hmid[KPP][RR];
    __shared__ int tpi[KPP];
    __shared__ float tpw[KPP];

    float a = aggp[t*DD+tid];
    float cx = ctxp[t*DD+tid];
    mix[tid] = 0.03125f * a + 0.5f * cx;   // 0.5/sqrt(256) = 0.03125
    float cb = n2p[t*DD+tid] + a;
    comb[tid] = cb;
    combined[t*DD+tid] = cb;
    __syncthreads();

    // pattern scores: thread (p = tid&31, g = tid>>5) sums 32 elements
    {
        int p = tid & 31, g = tid >> 5;
        const float* pq = PQ + p*DD + g*32;
        const float* mp = mix + g*32;
        float acc = 0.f;
        #pragma unroll
        for (int d = 0; d < 32; ++d) acc = fmaf(mp[d], pq[d], acc);
        psp[g][p] = acc;
    }
    __syncthreads();
    if (tid < PP) {
        float s = 0.f;
        #pragma unroll
        for (int g = 0; g < 8; ++g) s += psp[g][tid];
        ps[tid] = s;
    }
    __syncthreads();

    // top-4 (ties -> lower index), softmax weights; all in LDS
    if (tid == 0) {
        float vals[KPP];
        #pragma unroll
        for (int it = 0; it < KPP; ++it) {
            float bv = -3.4e38f; int bi = 0;
            for (int p = 0; p < PP; ++p) { float v = ps[p]; if (v > bv) { bv = v; bi = p; } }
            vals[it] = bv; tpi[it] = bi; ps[bi] = -3.4e38f;
        }
        float mx = vals[0], sum = 0.f;
        float e0 = expf(vals[0]-mx), e1 = expf(vals[1]-mx),
              e2 = expf(vals[2]-mx), e3 = expf(vals[3]-mx);
        sum = e0+e1+e2+e3;
        float is = 1.0f/sum;
        tpw[0]=e0*is; tpw[1]=e1*is; tpw[2]=e2*is; tpw[3]=e3*is;
    }
    __syncthreads();

    // hmid[kp][r] = tpw[kp] * (comb . Aup[tpi[kp]][:,r])
    {
        int kp = tid >> 6, r = tid & 63;
        const float* Ap = Aup + (size_t)tpi[kp]*(DD*RR) + r;
        float acc = 0.f;
        #pragma unroll 8
        for (int d = 0; d < DD; ++d) acc = fmaf(comb[d], Ap[(size_t)d*RR], acc);
        hmid[kp][r] = acc * tpw[kp];
    }
    __syncthreads();

    // h_pattern[t, 4*tid .. 4*tid+3] : float4 loads of B, coalesced
    {
        float4 acc = make_float4(0.f, 0.f, 0.f, 0.f);
        #pragma unroll
        for (int kp = 0; kp < KPP; ++kp) {
            const float4* Bp = (const float4*)(Bup + (size_t)tpi[kp]*(RR*FFD)) + tid;
            const float* hm = hmid[kp];
            #pragma unroll 8
            for (int r = 0; r < RR; ++r) {
                float4 b = Bp[(size_t)r*(FFD/4)];
                float h = hm[r];
                acc.x = fmaf(h, b.x, acc.x);
                acc.y = fmaf(h, b.y, acc.y);
                acc.z = fmaf(h, b.z, acc.z);
                acc.w = fmaf(h, b.w, acc.w);
            }
        }
        ((float4*)(hpat + (size_t)t*FFD))[tid] = acc;
    }
}

// ---------------------------------------------------------------------------
extern "C" void kernel_launch(void* const* d_in, const int* in_sizes, int n_in,
                              void* d_out, int out_size, void* d_ws, size_t ws_size,
                              hipStream_t stream)
{
    const float* x        = (const float*)d_in[0];
    const float* g1       = (const float*)d_in[1];
    const float* b1       = (const float*)d_in[2];
    const float* g2       = (const float*)d_in[3];
    const float* b2       = (const float*)d_in[4];
    const float* Wq       = (const float*)d_in[5];
    const float* bq       = (const float*)d_in[6];
    const float* Wk       = (const float*)d_in[7];
    const float* bk       = (const float*)d_in[8];
    const float* Wv       = (const float*)d_in[9];
    const float* bv       = (const float*)d_in[10];
    const float* Wpath    = (const float*)d_in[11];
    const float* bpath    = (const float*)d_in[12];
    const float* neurons  = (const float*)d_in[13];
    const float* Wnq      = (const float*)d_in[14];
    const float* bnq      = (const float*)d_in[15];
    const float* Wnk      = (const float*)d_in[16];
    const float* bnk      = (const float*)d_in[17];
    const float* Wnv      = (const float*)d_in[18];
    const float* bnv      = (const float*)d_in[19];
    const float* PQ       = (const float*)d_in[20];
    const float* Aup      = (const float*)d_in[21];
    const float* Bup      = (const float*)d_in[22];
    const float* Wub      = (const float*)d_in[23];
    const float* bub      = (const float*)d_in[24];
    const float* Wd       = (const float*)d_in[25];
    const float* bd       = (const float*)d_in[26];

    float* out0    = (float*)d_out;              // [B,S,D] residual output
    float* out_idx = out0 + (size_t)TT*DD;       // [B,S,K] indices (as float)

    // workspace carve-up (floats)
    float* ws = (float*)d_ws;
    float* n1   = ws; ws += TT*DD;
    float* n2   = ws; ws += TT*DD;
    float* qb   = ws; ws += TT*DD;
    float* kb   = ws; ws += TT*DD;
    float* vb   = ws; ws += TT*DD;
    float* ctx  = ws; ws += TT*DD;
    float* ts   = ws; ws += TT*NN;
    float* cs   = ws; ws += TT*NN;
    float* nqa  = ws; ws += NN*DD;
    float* nka  = ws; ws += NN*DD;
    float* nva  = ws; ws += NN*DD;
    float* agg  = ws; ws += TT*DD;
    float* comb = ws; ws += TT*DD;
    float* hpat = ws; ws += TT*FFD;
    float* hb   = ws; ws += TT*FFD;
    float* tkw  = ws; ws += TT*KK;
    int*   tki  = (int*)ws; ws += TT*KK;

    dim3 blk(256);

    // 1. LayerNorms
    ln_kernel<<<TT, blk, 0, stream>>>(x, g1, b1, g2, b2, n1, n2);

    // 2. QKV projections batched (M=1024,N=256,K=256, z=3)
    {
        GemmSet sq{n1, Wq, bq, qb, 0}, sk{n1, Wk, bk, kb, 0}, sv{n1, Wv, bv, vb, 0};
        gemm3_kernel<<<dim3(DD/64, TT/64, 3), blk, 0, stream>>>(sq, sk, sv, TT, DD, DD, 0);
    }

    // 3. Neuron projections batched (M=512,N=256,K=256, z=3); nv -> sigmoid
    {
        GemmSet s0{neurons, Wnq, bnq, nqa, 0}, s1{neurons, Wnk, bnk, nka, 0},
                s2{neurons, Wnv, bnv, nva, 1};
        gemm3_kernel<<<dim3(DD/64, NN/64, 3), blk, 0, stream>>>(s0, s1, s2, NN, DD, DD, 0);
    }

    // 4. Attention -> context
    attn_kernel<<<BB*HH*SS, blk, 0, stream>>>(qb, kb, vb, ctx);

    // 5. token/context scores vs neurons^T (M=1024,N=512,K=256, transB, z=2)
    {
        GemmSet s0{n1, neurons, nullptr, ts, 0}, s1{ctx, neurons, nullptr, cs, 0};
        gemm3_kernel<<<dim3(NN/64, TT/64, 2), blk, 0, stream>>>(s0, s1, s1, TT, NN, DD, 1);
    }

    // 6. path weights + mix + top-16
    route_kernel<<<TT, blk, 0, stream>>>(n1, ctx, Wpath, bpath, ts, cs, tki, tkw, out_idx);

    // 7. interaction FFN -> aggregated
    interact_kernel<<<TT, blk, 0, stream>>>(neurons, nqa, nka, nva, tki, tkw, agg);

    // 8. pattern LoRA -> combined, h_pattern
    pattern_kernel<<<TT, blk, 0, stream>>>(agg, ctx, n2, PQ, Aup, Bup, comb, hpat);

    // 9. h = gelu(0.1*(combined@Wub+bub) + 0.9*h_pattern)   (M=1024,N=1024,K=256)
    gemm_kernel<<<dim3(FFD/64, TT/64), blk, 0, stream>>>(comb, Wub, bub, hpat, hb, TT, FFD, DD, 0, 2);

    // 10. out = x + h@Wd + bd   (M=1024,N=256,K=1024) -> d_out
    gemm_kernel<<<dim3(DD/64, TT/64), blk, 0, stream>>>(hb, Wd, bd, x, out0, TT, DD, FFD, 0, 3);
}

// Round 3
// 513.053 us; speedup vs baseline: 2.8172x; 1.3061x over previous
//
#include <hip/hip_runtime.h>
#include <hip/hip_bf16.h>
#include <math.h>

// Problem dims (fixed)
#define BB 2
#define SS 512
#define DD 256
#define FFD 1024
#define HH 4
#define NN 512
#define PP 32
#define KK 16
#define KPP 4
#define RR 64
#define DHH 64
#define TT (BB*SS)   // 1024 tokens
#define QT 16        // attn queries per block

// ---------------------------------------------------------------------------
// LayerNorm: produces n1 = LN(x,g1,b1), n2 = LN(x,g2,b2). One block per token.
// ---------------------------------------------------------------------------
__global__ __launch_bounds__(256) void ln_kernel(
    const float* __restrict__ x,
    const float* __restrict__ g1, const float* __restrict__ b1,
    const float* __restrict__ g2, const float* __restrict__ b2,
    float* __restrict__ n1, float* __restrict__ n2)
{
    int t = blockIdx.x;
    int d = threadIdx.x;
    __shared__ float red[256];
    float v = x[t*DD + d];
    red[d] = v; __syncthreads();
    for (int s = 128; s > 0; s >>= 1) { if (d < s) red[d] += red[d+s]; __syncthreads(); }
    float mu = red[0] * (1.0f/DD);
    __syncthreads();
    float dv = v - mu;
    red[d] = dv*dv; __syncthreads();
    for (int s = 128; s > 0; s >>= 1) { if (d < s) red[d] += red[d+s]; __syncthreads(); }
    float var = red[0] * (1.0f/DD);
    float r = 1.0f / sqrtf(var + 1e-5f);
    n1[t*DD+d] = dv*r*g1[d] + b1[d];
    n2[t*DD+d] = dv*r*g2[d] + b2[d];
}

// ---------------------------------------------------------------------------
// Shared GEMM body: C[M,N] = epilogue( A[M,K] @ B + bias )
//   transB==0: B is [K,N] row-major ; transB==1: B is [N,K] row-major
//   mode 0: none; 1: sigmoid; 2: gelu(0.1*val + 0.9*extra); 3: val + extra
// Tiles: 64x64, BK=16, 256 threads, 4x4 per-thread microtile.
// ---------------------------------------------------------------------------
__device__ __forceinline__ void gemm_body(
    const float* __restrict__ A, const float* __restrict__ Bm,
    const float* __restrict__ bias, const float* __restrict__ extra,
    float* __restrict__ C, int M, int Nn, int Kk, int transB, int mode)
{
    __shared__ float As[16][65];
    __shared__ float Bs[16][65];
    int bm = blockIdx.y * 64;
    int bn = blockIdx.x * 64;
    int tid = threadIdx.x;
    int tx = tid & 15, ty = tid >> 4;
    float acc[4][4] = {};
    for (int k0 = 0; k0 < Kk; k0 += 16) {
        #pragma unroll
        for (int e = 0; e < 4; ++e) {
            int lin = e*256 + tid;
            int c = lin & 15, r = lin >> 4;
            As[c][r] = A[(size_t)(bm + r) * Kk + k0 + c];
        }
        if (transB == 0) {
            #pragma unroll
            for (int e = 0; e < 4; ++e) {
                int lin = e*256 + tid;
                int r = lin & 63, c = lin >> 6;
                Bs[c][r] = Bm[(size_t)(k0 + c) * Nn + bn + r];
            }
        } else {
            #pragma unroll
            for (int e = 0; e < 4; ++e) {
                int lin = e*256 + tid;
                int c = lin & 15, r = lin >> 4;
                Bs[c][r] = Bm[(size_t)(bn + r) * Kk + k0 + c];
            }
        }
        __syncthreads();
        #pragma unroll
        for (int kk = 0; kk < 16; ++kk) {
            float a[4], b[4];
            #pragma unroll
            for (int i = 0; i < 4; ++i) a[i] = As[kk][ty*4+i];
            #pragma unroll
            for (int j = 0; j < 4; ++j) b[j] = Bs[kk][tx*4+j];
            #pragma unroll
            for (int i = 0; i < 4; ++i)
                #pragma unroll
                for (int j = 0; j < 4; ++j)
                    acc[i][j] = fmaf(a[i], b[j], acc[i][j]);
        }
        __syncthreads();
    }
    #pragma unroll
    for (int i = 0; i < 4; ++i) {
        int m = bm + ty*4 + i;
        #pragma unroll
        for (int j = 0; j < 4; ++j) {
            int n = bn + tx*4 + j;
            float val = acc[i][j] + (bias ? bias[n] : 0.0f);
            if (mode == 1) {
                val = 1.0f / (1.0f + expf(-val));
            } else if (mode == 2) {
                float z = 0.1f*val + 0.9f*extra[(size_t)m*Nn+n];
                val = 0.5f*z*(1.0f + erff(z*0.70710678118654752f));
            } else if (mode == 3) {
                val = val + extra[(size_t)m*Nn+n];
            }
            C[(size_t)m*Nn + n] = val;
        }
    }
}

__global__ __launch_bounds__(256) void gemm_kernel(
    const float* __restrict__ A, const float* __restrict__ Bm,
    const float* __restrict__ bias, const float* __restrict__ extra,
    float* __restrict__ C, int M, int Nn, int Kk, int transB, int mode)
{
    gemm_body(A, Bm, bias, extra, C, M, Nn, Kk, transB, mode);
}

// Batched-by-z variant: up to 3 independent (A,B,bias,C,mode) sets, same shape.
struct GemmSet { const float* A; const float* B; const float* bias; float* C; int mode; };

__global__ __launch_bounds__(256) void gemm3_kernel(
    GemmSet s0, GemmSet s1, GemmSet s2, int M, int Nn, int Kk, int transB)
{
    GemmSet s = (blockIdx.z == 0) ? s0 : ((blockIdx.z == 1) ? s1 : s2);
    gemm_body(s.A, s.B, s.bias, nullptr, s.C, M, Nn, Kk, transB, s.mode);
}

// ---------------------------------------------------------------------------
// Flash-style attention: block = (b, h, 16-query tile). 256 blocks, 256 thr.
// Each thread owns ONE query (qo=tid>>4) for both QK and PV phases; k/d slice
// c=tid&15. Online softmax m/l in registers; shfl_xor reduce over 16 lanes.
// ---------------------------------------------------------------------------
__global__ __launch_bounds__(256) void attn_kernel(
    const float* __restrict__ q, const float* __restrict__ k,
    const float* __restrict__ v, float* __restrict__ ctx)
{
    int bi = blockIdx.x;
    int qt = bi & 31;          // SS/QT = 32 tiles
    int bh = bi >> 5;
    int h = bh & (HH-1);
    int b = bh >> 2;
    int tid = threadIdx.x;
    int qo = tid >> 4;         // 0..15: this thread's query
    int c  = tid & 15;         // k-group (QK) / d-group (PV)

    __shared__ float Qs[QT][68];    // padded, broadcast reads
    __shared__ float Kt[64][64];    // transposed: Kt[d][k], b128 over k
    __shared__ float Vs[64][68];    // row-major, b128 over d
    __shared__ float Ps[QT][68];

    {
        const float* qp = q + ((size_t)(b*SS + qt*QT + qo)*DD) + h*DHH + c*4;
        *(float4*)&Qs[qo][c*4] = *(const float4*)qp;
    }
    float O0=0.f, O1=0.f, O2=0.f, O3=0.f;
    float mreg = -3.4e38f, lreg = 0.f;

    for (int t = 0; t < 8; ++t) {
        if (t) __syncthreads();   // prev PV done before overwriting tiles
        #pragma unroll
        for (int e = 0; e < 4; ++e) {
            int lin = e*256 + tid;
            int kr = lin & 63;        // K: row per lane -> store bank = lane%32
            int c4 = lin >> 6;        // 0..15
            const float* kp = k + ((size_t)(b*SS + t*64 + kr)*DD) + h*DHH + c4*4;
            float4 kv = *(const float4*)kp;
            Kt[c4*4+0][kr] = kv.x;
            Kt[c4*4+1][kr] = kv.y;
            Kt[c4*4+2][kr] = kv.z;
            Kt[c4*4+3][kr] = kv.w;
            int vr = lin >> 4;        // V: coalesced load, direct store
            int vc = lin & 15;
            const float* vp = v + ((size_t)(b*SS + t*64 + vr)*DD) + h*DHH + vc*4;
            *(float4*)&Vs[vr][vc*4] = *(const float4*)vp;
        }
        __syncthreads();
        // QK^T: this thread -> scores for q=qo, k = c*4 .. c*4+3
        float s0=0.f, s1=0.f, s2=0.f, s3=0.f;
        #pragma unroll 8
        for (int d = 0; d < 64; ++d) {
            float qv = Qs[qo][d];
            float4 kv = *(const float4*)&Kt[d][c*4];
            s0 = fmaf(qv, kv.x, s0);
            s1 = fmaf(qv, kv.y, s1);
            s2 = fmaf(qv, kv.z, s2);
            s3 = fmaf(qv, kv.w, s3);
        }
        s0 *= 0.125f; s1 *= 0.125f; s2 *= 0.125f; s3 *= 0.125f;
        float mx = fmaxf(fmaxf(s0, s1), fmaxf(s2, s3));
        #pragma unroll
        for (int mk = 1; mk <= 8; mk <<= 1)
            mx = fmaxf(mx, __shfl_xor(mx, mk));
        float mnew = fmaxf(mreg, mx);
        float scl = __expf(mreg - mnew);
        float e0 = __expf(s0 - mnew), e1 = __expf(s1 - mnew),
              e2 = __expf(s2 - mnew), e3 = __expf(s3 - mnew);
        float esum = e0 + e1 + e2 + e3;
        #pragma unroll
        for (int mk = 1; mk <= 8; mk <<= 1)
            esum += __shfl_xor(esum, mk);
        lreg = lreg * scl + esum;
        mreg = mnew;
        float4 pw; pw.x = e0; pw.y = e1; pw.z = e2; pw.w = e3;
        *(float4*)&Ps[qo][c*4] = pw;
        __syncthreads();
        // rescale O, then PV over this tile (d-slice = c*4..c*4+3)
        O0 *= scl; O1 *= scl; O2 *= scl; O3 *= scl;
        #pragma unroll 8
        for (int kk = 0; kk < 64; ++kk) {
            float pv = Ps[qo][kk];
            float4 vv = *(const float4*)&Vs[kk][c*4];
            O0 = fmaf(pv, vv.x, O0);
            O1 = fmaf(pv, vv.y, O1);
            O2 = fmaf(pv, vv.z, O2);
            O3 = fmaf(pv, vv.w, O3);
        }
    }
    float linv = 1.0f / lreg;
    float4 o4; o4.x = O0*linv; o4.y = O1*linv; o4.z = O2*linv; o4.w = O3*linv;
    *(float4*)(ctx + ((size_t)(b*SS + qt*QT + qo)*DD) + h*DHH + c*4) = o4;
}

// ---------------------------------------------------------------------------
// Path softmax + score mix + stable top-16 + softmax weights. Block per token.
// ---------------------------------------------------------------------------
__global__ __launch_bounds__(256) void route_kernel(
    const float* __restrict__ n1, const float* __restrict__ ctx,
    const float* __restrict__ Wpath, const float* __restrict__ bpath,
    const float* __restrict__ ts, const float* __restrict__ cs,
    int* __restrict__ topk_idx, float* __restrict__ topk_w,
    float* __restrict__ out_idx)
{
    int t = blockIdx.x, tid = threadIdx.x;
    __shared__ float red0[256], red1[256];
    float a = n1[t*DD+tid], c = ctx[t*DD+tid];
    red0[tid] = a * Wpath[tid*2+0] + c * Wpath[(DD+tid)*2+0];
    red1[tid] = a * Wpath[tid*2+1] + c * Wpath[(DD+tid)*2+1];
    __syncthreads();
    for (int s = 128; s > 0; s >>= 1) {
        if (tid < s) { red0[tid] += red0[tid+s]; red1[tid] += red1[tid+s]; }
        __syncthreads();
    }
    __shared__ float w0s, w1s;
    if (tid == 0) {
        float l0 = red0[0] + bpath[0], l1 = red1[0] + bpath[1];
        float mm = fmaxf(l0, l1);
        float e0 = expf(l0-mm), e1 = expf(l1-mm);
        float is = 1.0f/(e0+e1);
        w0s = e0*is; w1s = e1*is;
    }
    __syncthreads();
    float w0 = w0s, w1 = w1s;
    __shared__ float sc[NN];
    sc[tid]     = w0*ts[t*NN+tid]     + w1*cs[t*NN+tid];
    sc[tid+256] = w0*ts[t*NN+tid+256] + w1*cs[t*NN+tid+256];
    __syncthreads();
    __shared__ float bv_[256]; __shared__ int bi_[256];
    __shared__ float selv[KK]; __shared__ int seli[KK];
    for (int it = 0; it < KK; ++it) {
        float v0 = sc[tid], v1 = sc[tid+256];
        float bv; int bi;
        if (v0 >= v1) { bv = v0; bi = tid; } else { bv = v1; bi = tid+256; }
        bv_[tid] = bv; bi_[tid] = bi;
        __syncthreads();
        for (int s = 128; s > 0; s >>= 1) {
            if (tid < s) {
                float ov = bv_[tid+s]; int oi = bi_[tid+s];
                if (ov > bv_[tid] || (ov == bv_[tid] && oi < bi_[tid])) { bv_[tid] = ov; bi_[tid] = oi; }
            }
            __syncthreads();
        }
        if (tid == 0) { selv[it] = bv_[0]; seli[it] = bi_[0]; sc[bi_[0]] = -3.4e38f; }
        __syncthreads();
    }
    if (tid == 0) {
        float mx = selv[0];
        float e[KK]; float sum = 0.f;
        for (int i = 0; i < KK; ++i) { e[i] = expf(selv[i]-mx); sum += e[i]; }
        float is = 1.0f/sum;
        for (int i = 0; i < KK; ++i) {
            topk_idx[t*KK+i] = seli[i];
            topk_w[t*KK+i]   = e[i]*is;
            out_idx[t*KK+i]  = (float)seli[i];
        }
    }
}

// ---------------------------------------------------------------------------
// InteractionFFN: block per token. LDS rows padded to 257 (bank-conflict fix:
// 256-stride put all 16 j-lanes on one bank in the QK phase).
// ---------------------------------------------------------------------------
__global__ __launch_bounds__(256) void interact_kernel(
    const float* __restrict__ neurons,
    const float* __restrict__ nqa, const float* __restrict__ nka,
    const float* __restrict__ nva,
    const int* __restrict__ topk_idx, const float* __restrict__ topk_w,
    float* __restrict__ agg)
{
    int t = blockIdx.x, tid = threadIdx.x;
    __shared__ float nq[KK][DD+1];
    __shared__ float nk[KK][DD+1];
    __shared__ float nv[KK][DD+1];
    __shared__ float ps[HH][KK][KK];
    __shared__ float tw[KK];
    __shared__ int sidx[KK];
    if (tid < KK) { tw[tid] = topk_w[t*KK+tid]; sidx[tid] = topk_idx[t*KK+tid]; }
    __syncthreads();
    for (int i = 0; i < KK; ++i) {
        int idx = sidx[i];
        nq[i][tid] = nqa[idx*DD+tid];
        nk[i][tid] = nka[idx*DD+tid];
        nv[i][tid] = nva[idx*DD+tid];
    }
    __syncthreads();
    #pragma unroll
    for (int r = 0; r < 4; ++r) {
        int lin = r*256 + tid;         // (h,i,j)
        int j = lin & 15, i = (lin >> 4) & 15, h = lin >> 8;
        const float* qp = &nq[i][h*DHH];
        const float* kp = &nk[j][h*DHH];
        float acc = 0.f;
        #pragma unroll 8
        for (int d = 0; d < DHH; ++d) acc = fmaf(qp[d], kp[d], acc);
        ps[h][i][j] = acc * 0.125f;
    }
    __syncthreads();
    if (tid < 64) {                     // softmax over j for each (h,i)
        int h = tid >> 4, i = tid & 15;
        float mx = -3.4e38f;
        for (int j = 0; j < KK; ++j) mx = fmaxf(mx, ps[h][i][j]);
        float sum = 0.f;
        for (int j = 0; j < KK; ++j) { float e = expf(ps[h][i][j]-mx); ps[h][i][j] = e; sum += e; }
        float is = 1.0f/sum;
        for (int j = 0; j < KK; ++j) ps[h][i][j] *= is;
    }
    __syncthreads();
    int d = tid, h = d >> 6;
    float acc = 0.f;
    for (int i = 0; i < KK; ++i) {
        float g = 0.f;
        #pragma unroll
        for (int j = 0; j < KK; ++j) g = fmaf(ps[h][i][j], nv[j][d], g);
        acc += tw[i] * neurons[sidx[i]*DD + d] * g;
    }
    agg[t*DD+d] = acc;
}

// ---------------------------------------------------------------------------
// Pattern stage: block per token.
// ---------------------------------------------------------------------------
__global__ __launch_bounds__(256) void pattern_kernel(
    const float* __restrict__ aggp, const float* __restrict__ ctxp,
    const float* __restrict__ n2p, const float* __restrict__ PQ,
    const float* __restrict__ Aup, const float* __restrict__ Bup,
    float* __restrict__ combined, float* __restrict__ hpat)
{
    int t = blockIdx.x, tid = threadIdx.x;
    __shared__ float mix[DD], comb[DD];
    __shared__ float ps[PP];
    __shared__ float psp[8][33];
    __shared__ float hmid[KPP][RR];
    __shared__ int tpi[KPP];
    __shared__ float tpw[KPP];

    float a = aggp[t*DD+tid];
    float cx = ctxp[t*DD+tid];
    mix[tid] = 0.03125f * a + 0.5f * cx;   // 0.5/sqrt(256) = 0.03125
    float cb = n2p[t*DD+tid] + a;
    comb[tid] = cb;
    combined[t*DD+tid] = cb;
    __syncthreads();

    {
        int p = tid & 31, g = tid >> 5;
        const float* pq = PQ + p*DD + g*32;
        const float* mp = mix + g*32;
        float acc = 0.f;
        #pragma unroll
        for (int d = 0; d < 32; ++d) acc = fmaf(mp[d], pq[d], acc);
        psp[g][p] = acc;
    }
    __syncthreads();
    if (tid < PP) {
        float s = 0.f;
        #pragma unroll
        for (int g = 0; g < 8; ++g) s += psp[g][tid];
        ps[tid] = s;
    }
    __syncthreads();

    if (tid == 0) {
        float vals[KPP];
        #pragma unroll
        for (int it = 0; it < KPP; ++it) {
            float bv = -3.4e38f; int bi = 0;
            for (int p = 0; p < PP; ++p) { float v = ps[p]; if (v > bv) { bv = v; bi = p; } }
            vals[it] = bv; tpi[it] = bi; ps[bi] = -3.4e38f;
        }
        float mx = vals[0];
        float e0 = expf(vals[0]-mx), e1 = expf(vals[1]-mx),
              e2 = expf(vals[2]-mx), e3 = expf(vals[3]-mx);
        float is = 1.0f/(e0+e1+e2+e3);
        tpw[0]=e0*is; tpw[1]=e1*is; tpw[2]=e2*is; tpw[3]=e3*is;
    }
    __syncthreads();

    {
        int kp = tid >> 6, r = tid & 63;
        const float* Ap = Aup + (size_t)tpi[kp]*(DD*RR) + r;
        float acc = 0.f;
        #pragma unroll 8
        for (int d = 0; d < DD; ++d) acc = fmaf(comb[d], Ap[(size_t)d*RR], acc);
        hmid[kp][r] = acc * tpw[kp];
    }
    __syncthreads();

    {
        float4 acc = make_float4(0.f, 0.f, 0.f, 0.f);
        #pragma unroll
        for (int kp = 0; kp < KPP; ++kp) {
            const float4* Bp = (const float4*)(Bup + (size_t)tpi[kp]*(RR*FFD)) + tid;
            const float* hm = hmid[kp];
            #pragma unroll 8
            for (int r = 0; r < RR; ++r) {
                float4 b = Bp[(size_t)r*(FFD/4)];
                float h = hm[r];
                acc.x = fmaf(h, b.x, acc.x);
                acc.y = fmaf(h, b.y, acc.y);
                acc.z = fmaf(h, b.z, acc.z);
                acc.w = fmaf(h, b.w, acc.w);
            }
        }
        ((float4*)(hpat + (size_t)t*FFD))[tid] = acc;
    }
}

// ---------------------------------------------------------------------------
extern "C" void kernel_launch(void* const* d_in, const int* in_sizes, int n_in,
                              void* d_out, int out_size, void* d_ws, size_t ws_size,
                              hipStream_t stream)
{
    const float* x        = (const float*)d_in[0];
    const float* g1       = (const float*)d_in[1];
    const float* b1       = (const float*)d_in[2];
    const float* g2       = (const float*)d_in[3];
    const float* b2       = (const float*)d_in[4];
    const float* Wq       = (const float*)d_in[5];
    const float* bq       = (const float*)d_in[6];
    const float* Wk       = (const float*)d_in[7];
    const float* bk       = (const float*)d_in[8];
    const float* Wv       = (const float*)d_in[9];
    const float* bv       = (const float*)d_in[10];
    const float* Wpath    = (const float*)d_in[11];
    const float* bpath    = (const float*)d_in[12];
    const float* neurons  = (const float*)d_in[13];
    const float* Wnq      = (const float*)d_in[14];
    const float* bnq      = (const float*)d_in[15];
    const float* Wnk      = (const float*)d_in[16];
    const float* bnk      = (const float*)d_in[17];
    const float* Wnv      = (const float*)d_in[18];
    const float* bnv      = (const float*)d_in[19];
    const float* PQ       = (const float*)d_in[20];
    const float* Aup      = (const float*)d_in[21];
    const float* Bup      = (const float*)d_in[22];
    const float* Wub      = (const float*)d_in[23];
    const float* bub      = (const float*)d_in[24];
    const float* Wd       = (const float*)d_in[25];
    const float* bd       = (const float*)d_in[26];

    float* out0    = (float*)d_out;              // [B,S,D] residual output
    float* out_idx = out0 + (size_t)TT*DD;       // [B,S,K] indices (as float)

    // workspace carve-up (floats)
    float* ws = (float*)d_ws;
    float* n1   = ws; ws += TT*DD;
    float* n2   = ws; ws += TT*DD;
    float* qb   = ws; ws += TT*DD;
    float* kb   = ws; ws += TT*DD;
    float* vb   = ws; ws += TT*DD;
    float* ctx  = ws; ws += TT*DD;
    float* ts   = ws; ws += TT*NN;
    float* cs   = ws; ws += TT*NN;
    float* nqa  = ws; ws += NN*DD;
    float* nka  = ws; ws += NN*DD;
    float* nva  = ws; ws += NN*DD;
    float* agg  = ws; ws += TT*DD;
    float* comb = ws; ws += TT*DD;
    float* hpat = ws; ws += TT*FFD;
    float* hb   = ws; ws += TT*FFD;
    float* tkw  = ws; ws += TT*KK;
    int*   tki  = (int*)ws; ws += TT*KK;

    dim3 blk(256);

    // 1. LayerNorms
    ln_kernel<<<TT, blk, 0, stream>>>(x, g1, b1, g2, b2, n1, n2);

    // 2. QKV projections batched (M=1024,N=256,K=256, z=3)
    {
        GemmSet sq{n1, Wq, bq, qb, 0}, sk{n1, Wk, bk, kb, 0}, sv{n1, Wv, bv, vb, 0};
        gemm3_kernel<<<dim3(DD/64, TT/64, 3), blk, 0, stream>>>(sq, sk, sv, TT, DD, DD, 0);
    }

    // 3. Neuron projections batched (M=512,N=256,K=256, z=3); nv -> sigmoid
    {
        GemmSet s0{neurons, Wnq, bnq, nqa, 0}, s1{neurons, Wnk, bnk, nka, 0},
                s2{neurons, Wnv, bnv, nva, 1};
        gemm3_kernel<<<dim3(DD/64, NN/64, 3), blk, 0, stream>>>(s0, s1, s2, NN, DD, DD, 0);
    }

    // 4. Attention -> context  (flash-style, 256 blocks)
    attn_kernel<<<BB*HH*(SS/QT), blk, 0, stream>>>(qb, kb, vb, ctx);

    // 5. token/context scores vs neurons^T (M=1024,N=512,K=256, transB, z=2)
    {
        GemmSet s0{n1, neurons, nullptr, ts, 0}, s1{ctx, neurons, nullptr, cs, 0};
        gemm3_kernel<<<dim3(NN/64, TT/64, 2), blk, 0, stream>>>(s0, s1, s1, TT, NN, DD, 1);
    }

    // 6. path weights + mix + top-16
    route_kernel<<<TT, blk, 0, stream>>>(n1, ctx, Wpath, bpath, ts, cs, tki, tkw, out_idx);

    // 7. interaction FFN -> aggregated
    interact_kernel<<<TT, blk, 0, stream>>>(neurons, nqa, nka, nva, tki, tkw, agg);

    // 8. pattern LoRA -> combined, h_pattern
    pattern_kernel<<<TT, blk, 0, stream>>>(agg, ctx, n2, PQ, Aup, Bup, comb, hpat);

    // 9. h = gelu(0.1*(combined@Wub+bub) + 0.9*h_pattern)   (M=1024,N=1024,K=256)
    gemm_kernel<<<dim3(FFD/64, TT/64), blk, 0, stream>>>(comb, Wub, bub, hpat, hb, TT, FFD, DD, 0, 2);

    // 10. out = x + h@Wd + bd   (M=1024,N=256,K=1024) -> d_out
    gemm_kernel<<<dim3(DD/64, TT/64), blk, 0, stream>>>(hb, Wd, bd, x, out0, TT, DD, FFD, 0, 3);
}

// Round 4
// 318.860 us; speedup vs baseline: 4.5330x; 1.6090x over previous
//
#include <hip/hip_runtime.h>
#include <hip/hip_bf16.h>
#include <math.h>

// Problem dims (fixed)
#define BB 2
#define SS 512
#define DD 256
#define FFD 1024
#define HH 4
#define NN 512
#define PP 32
#define KK 16
#define KPP 4
#define RR 64
#define DHH 64
#define TT (BB*SS)   // 1024 tokens
#define QT 16        // attn queries per block

// ---------------------------------------------------------------------------
// LayerNorm: produces n1 = LN(x,g1,b1), n2 = LN(x,g2,b2). One block per token.
// ---------------------------------------------------------------------------
__global__ __launch_bounds__(256) void ln_kernel(
    const float* __restrict__ x,
    const float* __restrict__ g1, const float* __restrict__ b1,
    const float* __restrict__ g2, const float* __restrict__ b2,
    float* __restrict__ n1, float* __restrict__ n2)
{
    int t = blockIdx.x;
    int d = threadIdx.x;
    __shared__ float red[256];
    float v = x[t*DD + d];
    red[d] = v; __syncthreads();
    for (int s = 128; s > 0; s >>= 1) { if (d < s) red[d] += red[d+s]; __syncthreads(); }
    float mu = red[0] * (1.0f/DD);
    __syncthreads();
    float dv = v - mu;
    red[d] = dv*dv; __syncthreads();
    for (int s = 128; s > 0; s >>= 1) { if (d < s) red[d] += red[d+s]; __syncthreads(); }
    float var = red[0] * (1.0f/DD);
    float r = 1.0f / sqrtf(var + 1e-5f);
    n1[t*DD+d] = dv*r*g1[d] + b1[d];
    n2[t*DD+d] = dv*r*g2[d] + b2[d];
}

// ---------------------------------------------------------------------------
// GEMM body v2: 64x64 tile, BK=32, 256 threads, register double-buffering,
// single barrier per K-step, float4 LDS fragment reads.
//   C[M,N] = epilogue( A[M, k0off..k0off+kLen] @ B + bias )
//   transB==0: B is [K,N] row-major ; transB==1: B is [N,K] row-major
//   mode 0: none; 1: sigmoid; 2: gelu(0.1*val+0.9*extra); 3: val+extra
// ---------------------------------------------------------------------------
__device__ __forceinline__ void gemm_body(
    const float* __restrict__ A, const float* __restrict__ Bm,
    const float* __restrict__ bias, const float* __restrict__ extra,
    float* __restrict__ C, int M, int Nn, int Kk, int transB, int mode,
    int k0off, int kLen)
{
    __shared__ float As[2][32][68];   // As[buf][k][m] (transposed)
    __shared__ float Bs[2][32][68];   // Bs[buf][k][n]
    int bm = blockIdx.y * 64;
    int bn = blockIdx.x * 64;
    int tid = threadIdx.x;
    int tx = tid & 15, ty = tid >> 4;

    float4 pa[2], pb[2];

    // ---- tile load/store helpers ----
    // A: 64 rows x 32 cols = 512 float4; thread e: row = e*32 + (tid>>3), c4 = tid&7
    // B (transB=0): 32 rows x 64 cols; thread e: k = e*16 + (tid>>4), n4 = tid&15
    // B (transB=1): 64 rows(n) x 32 cols(k); like A.
    #define LOAD_A(kbase) { \
        _Pragma("unroll") \
        for (int e = 0; e < 2; ++e) { \
            int r = e*32 + (tid>>3); int c4 = tid & 7; \
            pa[e] = *(const float4*)&A[(size_t)(bm + r)*Kk + (kbase) + c4*4]; \
        } }
    #define STORE_A(buf) { \
        _Pragma("unroll") \
        for (int e = 0; e < 2; ++e) { \
            int r = e*32 + (tid>>3); int c4 = tid & 7; \
            As[buf][c4*4+0][r] = pa[e].x; \
            As[buf][c4*4+1][r] = pa[e].y; \
            As[buf][c4*4+2][r] = pa[e].z; \
            As[buf][c4*4+3][r] = pa[e].w; \
        } }
    #define LOAD_B(kbase) { \
        if (transB == 0) { \
            _Pragma("unroll") \
            for (int e = 0; e < 2; ++e) { \
                int c = e*16 + (tid>>4); int n4 = tid & 15; \
                pb[e] = *(const float4*)&Bm[(size_t)((kbase) + c)*Nn + bn + n4*4]; \
            } \
        } else { \
            _Pragma("unroll") \
            for (int e = 0; e < 2; ++e) { \
                int r = e*32 + (tid>>3); int k4 = tid & 7; \
                pb[e] = *(const float4*)&Bm[(size_t)(bn + r)*Kk + (kbase) + k4*4]; \
            } \
        } }
    #define STORE_B(buf) { \
        if (transB == 0) { \
            _Pragma("unroll") \
            for (int e = 0; e < 2; ++e) { \
                int c = e*16 + (tid>>4); int n4 = tid & 15; \
                *(float4*)&Bs[buf][c][n4*4] = pb[e]; \
            } \
        } else { \
            _Pragma("unroll") \
            for (int e = 0; e < 2; ++e) { \
                int r = e*32 + (tid>>3); int k4 = tid & 7; \
                Bs[buf][k4*4+0][r] = pb[e].x; \
                Bs[buf][k4*4+1][r] = pb[e].y; \
                Bs[buf][k4*4+2][r] = pb[e].z; \
                Bs[buf][k4*4+3][r] = pb[e].w; \
            } \
        } }

    float acc[4][4] = {};
    int nk = kLen >> 5;   // BK=32

    LOAD_A(k0off); LOAD_B(k0off);
    STORE_A(0); STORE_B(0);
    __syncthreads();

    for (int kt = 0; kt < nk; ++kt) {
        int cur = kt & 1;
        if (kt + 1 < nk) { LOAD_A(k0off + (kt+1)*32); LOAD_B(k0off + (kt+1)*32); }
        #pragma unroll
        for (int kk = 0; kk < 32; ++kk) {
            float4 av = *(const float4*)&As[cur][kk][ty*4];
            float4 bv = *(const float4*)&Bs[cur][kk][tx*4];
            acc[0][0] = fmaf(av.x, bv.x, acc[0][0]);
            acc[0][1] = fmaf(av.x, bv.y, acc[0][1]);
            acc[0][2] = fmaf(av.x, bv.z, acc[0][2]);
            acc[0][3] = fmaf(av.x, bv.w, acc[0][3]);
            acc[1][0] = fmaf(av.y, bv.x, acc[1][0]);
            acc[1][1] = fmaf(av.y, bv.y, acc[1][1]);
            acc[1][2] = fmaf(av.y, bv.z, acc[1][2]);
            acc[1][3] = fmaf(av.y, bv.w, acc[1][3]);
            acc[2][0] = fmaf(av.z, bv.x, acc[2][0]);
            acc[2][1] = fmaf(av.z, bv.y, acc[2][1]);
            acc[2][2] = fmaf(av.z, bv.z, acc[2][2]);
            acc[2][3] = fmaf(av.z, bv.w, acc[2][3]);
            acc[3][0] = fmaf(av.w, bv.x, acc[3][0]);
            acc[3][1] = fmaf(av.w, bv.y, acc[3][1]);
            acc[3][2] = fmaf(av.w, bv.z, acc[3][2]);
            acc[3][3] = fmaf(av.w, bv.w, acc[3][3]);
        }
        if (kt + 1 < nk) {
            STORE_A(cur^1); STORE_B(cur^1);
            __syncthreads();
        }
    }

    #pragma unroll
    for (int i = 0; i < 4; ++i) {
        int m = bm + ty*4 + i;
        #pragma unroll
        for (int j = 0; j < 4; ++j) {
            int n = bn + tx*4 + j;
            float val = acc[i][j] + (bias ? bias[n] : 0.0f);
            if (mode == 1) {
                val = 1.0f / (1.0f + expf(-val));
            } else if (mode == 2) {
                float z = 0.1f*val + 0.9f*extra[(size_t)m*Nn+n];
                val = 0.5f*z*(1.0f + erff(z*0.70710678118654752f));
            } else if (mode == 3) {
                val = val + extra[(size_t)m*Nn+n];
            }
            C[(size_t)m*Nn + n] = val;
        }
    }
    #undef LOAD_A
    #undef STORE_A
    #undef LOAD_B
    #undef STORE_B
}

__global__ __launch_bounds__(256) void gemm_kernel(
    const float* __restrict__ A, const float* __restrict__ Bm,
    const float* __restrict__ bias, const float* __restrict__ extra,
    float* __restrict__ C, int M, int Nn, int Kk, int transB, int mode)
{
    gemm_body(A, Bm, bias, extra, C, M, Nn, Kk, transB, mode, 0, Kk);
}

// Batched-by-z variant: up to 3 independent (A,B,bias,C,mode) sets, same shape.
struct GemmSet { const float* A; const float* B; const float* bias; float* C; int mode; };

__global__ __launch_bounds__(256) void gemm3_kernel(
    GemmSet s0, GemmSet s1, GemmSet s2, int M, int Nn, int Kk, int transB)
{
    GemmSet s = (blockIdx.z == 0) ? s0 : ((blockIdx.z == 1) ? s1 : s2);
    gemm_body(s.A, s.B, s.bias, nullptr, s.C, M, Nn, Kk, transB, s.mode, 0, Kk);
}

// Split-K: blockIdx.z = K-slice; raw partials (no bias/epilogue) into Cpart.
__global__ __launch_bounds__(256) void gemm_splitk_kernel(
    const float* __restrict__ A, const float* __restrict__ Bm,
    float* __restrict__ Cpart, int M, int Nn, int Kk, int kPerSplit)
{
    int sk = blockIdx.z;
    float* Cp = Cpart + (size_t)sk * M * Nn;
    gemm_body(A, Bm, nullptr, nullptr, Cp, M, Nn, Kk, 0, 0, sk*kPerSplit, kPerSplit);
}

// out[t,d] = x[t,d] + bd[d] + sum_{sk<4} part[sk][t,d]
__global__ __launch_bounds__(256) void combine_wd_kernel(
    const float* __restrict__ part, const float* __restrict__ x,
    const float* __restrict__ bd, float* __restrict__ out)
{
    int i = blockIdx.x*256 + threadIdx.x;
    int d = i & (DD-1);
    float s = x[i] + bd[d];
    s += part[i] + part[i + TT*DD] + part[i + 2*TT*DD] + part[i + 3*TT*DD];
    out[i] = s;
}

// ---------------------------------------------------------------------------
// Flash-style attention: block = (b, h, 16-query tile). 256 blocks, 256 thr.
// ---------------------------------------------------------------------------
__global__ __launch_bounds__(256) void attn_kernel(
    const float* __restrict__ q, const float* __restrict__ k,
    const float* __restrict__ v, float* __restrict__ ctx)
{
    int bi = blockIdx.x;
    int qt = bi & 31;          // SS/QT = 32 tiles
    int bh = bi >> 5;
    int h = bh & (HH-1);
    int b = bh >> 2;
    int tid = threadIdx.x;
    int qo = tid >> 4;         // 0..15: this thread's query
    int c  = tid & 15;         // k-group (QK) / d-group (PV)

    __shared__ float Qs[QT][68];
    __shared__ float Kt[64][64];
    __shared__ float Vs[64][68];
    __shared__ float Ps[QT][68];

    {
        const float* qp = q + ((size_t)(b*SS + qt*QT + qo)*DD) + h*DHH + c*4;
        *(float4*)&Qs[qo][c*4] = *(const float4*)qp;
    }
    float O0=0.f, O1=0.f, O2=0.f, O3=0.f;
    float mreg = -3.4e38f, lreg = 0.f;

    for (int t = 0; t < 8; ++t) {
        if (t) __syncthreads();
        #pragma unroll
        for (int e = 0; e < 4; ++e) {
            int lin = e*256 + tid;
            int kr = lin & 63;
            int c4 = lin >> 6;
            const float* kp = k + ((size_t)(b*SS + t*64 + kr)*DD) + h*DHH + c4*4;
            float4 kv = *(const float4*)kp;
            Kt[c4*4+0][kr] = kv.x;
            Kt[c4*4+1][kr] = kv.y;
            Kt[c4*4+2][kr] = kv.z;
            Kt[c4*4+3][kr] = kv.w;
            int vr = lin >> 4;
            int vc = lin & 15;
            const float* vp = v + ((size_t)(b*SS + t*64 + vr)*DD) + h*DHH + vc*4;
            *(float4*)&Vs[vr][vc*4] = *(const float4*)vp;
        }
        __syncthreads();
        float s0=0.f, s1=0.f, s2=0.f, s3=0.f;
        #pragma unroll 8
        for (int d = 0; d < 64; ++d) {
            float qv = Qs[qo][d];
            float4 kv = *(const float4*)&Kt[d][c*4];
            s0 = fmaf(qv, kv.x, s0);
            s1 = fmaf(qv, kv.y, s1);
            s2 = fmaf(qv, kv.z, s2);
            s3 = fmaf(qv, kv.w, s3);
        }
        s0 *= 0.125f; s1 *= 0.125f; s2 *= 0.125f; s3 *= 0.125f;
        float mx = fmaxf(fmaxf(s0, s1), fmaxf(s2, s3));
        #pragma unroll
        for (int mk = 1; mk <= 8; mk <<= 1)
            mx = fmaxf(mx, __shfl_xor(mx, mk));
        float mnew = fmaxf(mreg, mx);
        float scl = __expf(mreg - mnew);
        float e0 = __expf(s0 - mnew), e1 = __expf(s1 - mnew),
              e2 = __expf(s2 - mnew), e3 = __expf(s3 - mnew);
        float esum = e0 + e1 + e2 + e3;
        #pragma unroll
        for (int mk = 1; mk <= 8; mk <<= 1)
            esum += __shfl_xor(esum, mk);
        lreg = lreg * scl + esum;
        mreg = mnew;
        float4 pw; pw.x = e0; pw.y = e1; pw.z = e2; pw.w = e3;
        *(float4*)&Ps[qo][c*4] = pw;
        __syncthreads();
        O0 *= scl; O1 *= scl; O2 *= scl; O3 *= scl;
        #pragma unroll 8
        for (int kk = 0; kk < 64; ++kk) {
            float pv = Ps[qo][kk];
            float4 vv = *(const float4*)&Vs[kk][c*4];
            O0 = fmaf(pv, vv.x, O0);
            O1 = fmaf(pv, vv.y, O1);
            O2 = fmaf(pv, vv.z, O2);
            O3 = fmaf(pv, vv.w, O3);
        }
    }
    float linv = 1.0f / lreg;
    float4 o4; o4.x = O0*linv; o4.y = O1*linv; o4.z = O2*linv; o4.w = O3*linv;
    *(float4*)(ctx + ((size_t)(b*SS + qt*QT + qo)*DD) + h*DHH + c*4) = o4;
}

// ---------------------------------------------------------------------------
// Path softmax + score mix + stable top-16 + softmax weights. Block per token.
// ---------------------------------------------------------------------------
__global__ __launch_bounds__(256) void route_kernel(
    const float* __restrict__ n1, const float* __restrict__ ctx,
    const float* __restrict__ Wpath, const float* __restrict__ bpath,
    const float* __restrict__ ts, const float* __restrict__ cs,
    int* __restrict__ topk_idx, float* __restrict__ topk_w,
    float* __restrict__ out_idx)
{
    int t = blockIdx.x, tid = threadIdx.x;
    __shared__ float red0[256], red1[256];
    float a = n1[t*DD+tid], c = ctx[t*DD+tid];
    red0[tid] = a * Wpath[tid*2+0] + c * Wpath[(DD+tid)*2+0];
    red1[tid] = a * Wpath[tid*2+1] + c * Wpath[(DD+tid)*2+1];
    __syncthreads();
    for (int s = 128; s > 0; s >>= 1) {
        if (tid < s) { red0[tid] += red0[tid+s]; red1[tid] += red1[tid+s]; }
        __syncthreads();
    }
    __shared__ float w0s, w1s;
    if (tid == 0) {
        float l0 = red0[0] + bpath[0], l1 = red1[0] + bpath[1];
        float mm = fmaxf(l0, l1);
        float e0 = expf(l0-mm), e1 = expf(l1-mm);
        float is = 1.0f/(e0+e1);
        w0s = e0*is; w1s = e1*is;
    }
    __syncthreads();
    float w0 = w0s, w1 = w1s;
    __shared__ float sc[NN];
    sc[tid]     = w0*ts[t*NN+tid]     + w1*cs[t*NN+tid];
    sc[tid+256] = w0*ts[t*NN+tid+256] + w1*cs[t*NN+tid+256];
    __syncthreads();
    __shared__ float bv_[256]; __shared__ int bi_[256];
    __shared__ float selv[KK]; __shared__ int seli[KK];
    for (int it = 0; it < KK; ++it) {
        float v0 = sc[tid], v1 = sc[tid+256];
        float bv; int bi;
        if (v0 >= v1) { bv = v0; bi = tid; } else { bv = v1; bi = tid+256; }
        bv_[tid] = bv; bi_[tid] = bi;
        __syncthreads();
        for (int s = 128; s > 0; s >>= 1) {
            if (tid < s) {
                float ov = bv_[tid+s]; int oi = bi_[tid+s];
                if (ov > bv_[tid] || (ov == bv_[tid] && oi < bi_[tid])) { bv_[tid] = ov; bi_[tid] = oi; }
            }
            __syncthreads();
        }
        if (tid == 0) { selv[it] = bv_[0]; seli[it] = bi_[0]; sc[bi_[0]] = -3.4e38f; }
        __syncthreads();
    }
    if (tid == 0) {
        float mx = selv[0];
        float e[KK]; float sum = 0.f;
        for (int i = 0; i < KK; ++i) { e[i] = expf(selv[i]-mx); sum += e[i]; }
        float is = 1.0f/sum;
        for (int i = 0; i < KK; ++i) {
            topk_idx[t*KK+i] = seli[i];
            topk_w[t*KK+i]   = e[i]*is;
            out_idx[t*KK+i]  = (float)seli[i];
        }
    }
}

// ---------------------------------------------------------------------------
// InteractionFFN: block per token (rows padded 257: bank-conflict-free).
// ---------------------------------------------------------------------------
__global__ __launch_bounds__(256) void interact_kernel(
    const float* __restrict__ neurons,
    const float* __restrict__ nqa, const float* __restrict__ nka,
    const float* __restrict__ nva,
    const int* __restrict__ topk_idx, const float* __restrict__ topk_w,
    float* __restrict__ agg)
{
    int t = blockIdx.x, tid = threadIdx.x;
    __shared__ float nq[KK][DD+1];
    __shared__ float nk[KK][DD+1];
    __shared__ float nv[KK][DD+1];
    __shared__ float ps[HH][KK][KK];
    __shared__ float tw[KK];
    __shared__ int sidx[KK];
    if (tid < KK) { tw[tid] = topk_w[t*KK+tid]; sidx[tid] = topk_idx[t*KK+tid]; }
    __syncthreads();
    for (int i = 0; i < KK; ++i) {
        int idx = sidx[i];
        nq[i][tid] = nqa[idx*DD+tid];
        nk[i][tid] = nka[idx*DD+tid];
        nv[i][tid] = nva[idx*DD+tid];
    }
    __syncthreads();
    #pragma unroll
    for (int r = 0; r < 4; ++r) {
        int lin = r*256 + tid;         // (h,i,j)
        int j = lin & 15, i = (lin >> 4) & 15, h = lin >> 8;
        const float* qp = &nq[i][h*DHH];
        const float* kp = &nk[j][h*DHH];
        float acc = 0.f;
        #pragma unroll 8
        for (int d = 0; d < DHH; ++d) acc = fmaf(qp[d], kp[d], acc);
        ps[h][i][j] = acc * 0.125f;
    }
    __syncthreads();
    if (tid < 64) {
        int h = tid >> 4, i = tid & 15;
        float mx = -3.4e38f;
        for (int j = 0; j < KK; ++j) mx = fmaxf(mx, ps[h][i][j]);
        float sum = 0.f;
        for (int j = 0; j < KK; ++j) { float e = expf(ps[h][i][j]-mx); ps[h][i][j] = e; sum += e; }
        float is = 1.0f/sum;
        for (int j = 0; j < KK; ++j) ps[h][i][j] *= is;
    }
    __syncthreads();
    int d = tid, h = d >> 6;
    float acc = 0.f;
    for (int i = 0; i < KK; ++i) {
        float g = 0.f;
        #pragma unroll
        for (int j = 0; j < KK; ++j) g = fmaf(ps[h][i][j], nv[j][d], g);
        acc += tw[i] * neurons[sidx[i]*DD + d] * g;
    }
    agg[t*DD+d] = acc;
}

// ---------------------------------------------------------------------------
// Pattern stage: block per token.
// ---------------------------------------------------------------------------
__global__ __launch_bounds__(256) void pattern_kernel(
    const float* __restrict__ aggp, const float* __restrict__ ctxp,
    const float* __restrict__ n2p, const float* __restrict__ PQ,
    const float* __restrict__ Aup, const float* __restrict__ Bup,
    float* __restrict__ combined, float* __restrict__ hpat)
{
    int t = blockIdx.x, tid = threadIdx.x;
    __shared__ float mix[DD], comb[DD];
    __shared__ float ps[PP];
    __shared__ float psp[8][33];
    __shared__ float hmid[KPP][RR];
    __shared__ int tpi[KPP];
    __shared__ float tpw[KPP];

    float a = aggp[t*DD+tid];
    float cx = ctxp[t*DD+tid];
    mix[tid] = 0.03125f * a + 0.5f * cx;
    float cb = n2p[t*DD+tid] + a;
    comb[tid] = cb;
    combined[t*DD+tid] = cb;
    __syncthreads();

    {
        int p = tid & 31, g = tid >> 5;
        const float* pq = PQ + p*DD + g*32;
        const float* mp = mix + g*32;
        float acc = 0.f;
        #pragma unroll
        for (int d = 0; d < 32; ++d) acc = fmaf(mp[d], pq[d], acc);
        psp[g][p] = acc;
    }
    __syncthreads();
    if (tid < PP) {
        float s = 0.f;
        #pragma unroll
        for (int g = 0; g < 8; ++g) s += psp[g][tid];
        ps[tid] = s;
    }
    __syncthreads();

    if (tid == 0) {
        float vals[KPP];
        #pragma unroll
        for (int it = 0; it < KPP; ++it) {
            float bv = -3.4e38f; int bi = 0;
            for (int p = 0; p < PP; ++p) { float v = ps[p]; if (v > bv) { bv = v; bi = p; } }
            vals[it] = bv; tpi[it] = bi; ps[bi] = -3.4e38f;
        }
        float mx = vals[0];
        float e0 = expf(vals[0]-mx), e1 = expf(vals[1]-mx),
              e2 = expf(vals[2]-mx), e3 = expf(vals[3]-mx);
        float is = 1.0f/(e0+e1+e2+e3);
        tpw[0]=e0*is; tpw[1]=e1*is; tpw[2]=e2*is; tpw[3]=e3*is;
    }
    __syncthreads();

    {
        int kp = tid >> 6, r = tid & 63;
        const float* Ap = Aup + (size_t)tpi[kp]*(DD*RR) + r;
        float acc = 0.f;
        #pragma unroll 8
        for (int d = 0; d < DD; ++d) acc = fmaf(comb[d], Ap[(size_t)d*RR], acc);
        hmid[kp][r] = acc * tpw[kp];
    }
    __syncthreads();

    {
        float4 acc = make_float4(0.f, 0.f, 0.f, 0.f);
        #pragma unroll
        for (int kp = 0; kp < KPP; ++kp) {
            const float4* Bp = (const float4*)(Bup + (size_t)tpi[kp]*(RR*FFD)) + tid;
            const float* hm = hmid[kp];
            #pragma unroll 8
            for (int r = 0; r < RR; ++r) {
                float4 b = Bp[(size_t)r*(FFD/4)];
                float h = hm[r];
                acc.x = fmaf(h, b.x, acc.x);
                acc.y = fmaf(h, b.y, acc.y);
                acc.z = fmaf(h, b.z, acc.z);
                acc.w = fmaf(h, b.w, acc.w);
            }
        }
        ((float4*)(hpat + (size_t)t*FFD))[tid] = acc;
    }
}

// ---------------------------------------------------------------------------
extern "C" void kernel_launch(void* const* d_in, const int* in_sizes, int n_in,
                              void* d_out, int out_size, void* d_ws, size_t ws_size,
                              hipStream_t stream)
{
    const float* x        = (const float*)d_in[0];
    const float* g1       = (const float*)d_in[1];
    const float* b1       = (const float*)d_in[2];
    const float* g2       = (const float*)d_in[3];
    const float* b2       = (const float*)d_in[4];
    const float* Wq       = (const float*)d_in[5];
    const float* bq       = (const float*)d_in[6];
    const float* Wk       = (const float*)d_in[7];
    const float* bk       = (const float*)d_in[8];
    const float* Wv       = (const float*)d_in[9];
    const float* bv       = (const float*)d_in[10];
    const float* Wpath    = (const float*)d_in[11];
    const float* bpath    = (const float*)d_in[12];
    const float* neurons  = (const float*)d_in[13];
    const float* Wnq      = (const float*)d_in[14];
    const float* bnq      = (const float*)d_in[15];
    const float* Wnk      = (const float*)d_in[16];
    const float* bnk      = (const float*)d_in[17];
    const float* Wnv      = (const float*)d_in[18];
    const float* bnv      = (const float*)d_in[19];
    const float* PQ       = (const float*)d_in[20];
    const float* Aup      = (const float*)d_in[21];
    const float* Bup      = (const float*)d_in[22];
    const float* Wub      = (const float*)d_in[23];
    const float* bub      = (const float*)d_in[24];
    const float* Wd       = (const float*)d_in[25];
    const float* bd       = (const float*)d_in[26];

    float* out0    = (float*)d_out;              // [B,S,D] residual output
    float* out_idx = out0 + (size_t)TT*DD;       // [B,S,K] indices (as float)

    // workspace carve-up (floats)
    float* ws = (float*)d_ws;
    float* n1   = ws; ws += TT*DD;
    float* n2   = ws; ws += TT*DD;
    float* qb   = ws; ws += TT*DD;
    float* kb   = ws; ws += TT*DD;
    float* vb   = ws; ws += TT*DD;
    float* ctx  = ws; ws += TT*DD;
    float* ts   = ws; ws += TT*NN;
    float* cs   = ws; ws += TT*NN;
    float* nqa  = ws; ws += NN*DD;
    float* nka  = ws; ws += NN*DD;
    float* nva  = ws; ws += NN*DD;
    float* agg  = ws; ws += TT*DD;
    float* comb = ws; ws += TT*DD;
    float* hpat = ws; ws += TT*FFD;
    float* hb   = ws; ws += TT*FFD;
    float* part = ws; ws += 4*TT*DD;             // split-K partials for Wd
    float* tkw  = ws; ws += TT*KK;
    int*   tki  = (int*)ws; ws += TT*KK;

    dim3 blk(256);

    // 1. LayerNorms
    ln_kernel<<<TT, blk, 0, stream>>>(x, g1, b1, g2, b2, n1, n2);

    // 2. QKV projections batched (M=1024,N=256,K=256, z=3)
    {
        GemmSet sq{n1, Wq, bq, qb, 0}, sk{n1, Wk, bk, kb, 0}, sv{n1, Wv, bv, vb, 0};
        gemm3_kernel<<<dim3(DD/64, TT/64, 3), blk, 0, stream>>>(sq, sk, sv, TT, DD, DD, 0);
    }

    // 3. Neuron projections batched (M=512,N=256,K=256, z=3); nv -> sigmoid
    {
        GemmSet s0{neurons, Wnq, bnq, nqa, 0}, s1{neurons, Wnk, bnk, nka, 0},
                s2{neurons, Wnv, bnv, nva, 1};
        gemm3_kernel<<<dim3(DD/64, NN/64, 3), blk, 0, stream>>>(s0, s1, s2, NN, DD, DD, 0);
    }

    // 4. Attention -> context  (flash-style, 256 blocks)
    attn_kernel<<<BB*HH*(SS/QT), blk, 0, stream>>>(qb, kb, vb, ctx);

    // 5. token/context scores vs neurons^T (M=1024,N=512,K=256, transB, z=2)
    {
        GemmSet s0{n1, neurons, nullptr, ts, 0}, s1{ctx, neurons, nullptr, cs, 0};
        gemm3_kernel<<<dim3(NN/64, TT/64, 2), blk, 0, stream>>>(s0, s1, s1, TT, NN, DD, 1);
    }

    // 6. path weights + mix + top-16
    route_kernel<<<TT, blk, 0, stream>>>(n1, ctx, Wpath, bpath, ts, cs, tki, tkw, out_idx);

    // 7. interaction FFN -> aggregated
    interact_kernel<<<TT, blk, 0, stream>>>(neurons, nqa, nka, nva, tki, tkw, agg);

    // 8. pattern LoRA -> combined, h_pattern
    pattern_kernel<<<TT, blk, 0, stream>>>(agg, ctx, n2, PQ, Aup, Bup, comb, hpat);

    // 9. h = gelu(0.1*(combined@Wub+bub) + 0.9*h_pattern)   (M=1024,N=1024,K=256)
    gemm_kernel<<<dim3(FFD/64, TT/64), blk, 0, stream>>>(comb, Wub, bub, hpat, hb, TT, FFD, DD, 0, 2);

    // 10. out = x + h@Wd + bd  via split-K(4) + combine  (M=1024,N=256,K=1024)
    gemm_splitk_kernel<<<dim3(DD/64, TT/64, 4), blk, 0, stream>>>(hb, Wd, part, TT, DD, FFD, FFD/4);
    combine_wd_kernel<<<TT*DD/256, blk, 0, stream>>>(part, x, bd, out0);
}